// Round 10
// baseline (220.598 us; speedup 1.0000x reference)
//
#include <hip/hip_runtime.h>

#define EPSF 1e-5f

// DPP move with old=0 (identity for add/max over nonnegative values; also
// provides the 0 boundary value for wave shifts).
#define DPPI(x, ctrl, rmask) \
    __builtin_amdgcn_update_dpp(0, (x), (ctrl), (rmask), 0xf, false)
#define DPPF(x, ctrl, rmask) \
    __builtin_bit_cast(float, __builtin_amdgcn_update_dpp(0, __builtin_bit_cast(int, (x)), (ctrl), (rmask), 0xf, false))

// Wave-wide shift-by-1 via gfx9 DPP (no DS pipe).
__device__ __forceinline__ float dpp_up1_f(float x) { return DPPF(x, 0x138, 0xf); }
__device__ __forceinline__ float dpp_dn1_f(float x) { return DPPF(x, 0x130, 0xf); }
__device__ __forceinline__ int   dpp_dn1_i(int   x) { return DPPI(x, 0x130, 0xf); }

// GCN wave64 inclusive scans: row_shr 1/2/4/8 + row_bcast:15 (rows 1,3) +
// row_bcast:31 (rows 2,3). Pure VALU. (Proven R3-R9.)
__device__ __forceinline__ float wscan_add_f(float x) {
    x += DPPF(x, 0x111, 0xf);
    x += DPPF(x, 0x112, 0xf);
    x += DPPF(x, 0x114, 0xf);
    x += DPPF(x, 0x118, 0xf);
    x += DPPF(x, 0x142, 0xa);
    x += DPPF(x, 0x143, 0xc);
    return x;
}
__device__ __forceinline__ int wscan_max_i(int x) {
    int y;
    y = DPPI(x, 0x111, 0xf); x = (x > y) ? x : y;
    y = DPPI(x, 0x112, 0xf); x = (x > y) ? x : y;
    y = DPPI(x, 0x114, 0xf); x = (x > y) ? x : y;
    y = DPPI(x, 0x118, 0xf); x = (x > y) ? x : y;
    y = DPPI(x, 0x142, 0xa); x = (x > y) ? x : y;
    y = DPPI(x, 0x143, 0xc); x = (x > y) ? x : y;
    return x;
}
__device__ __forceinline__ float readlane_f(float x, int l) {
    return __builtin_bit_cast(float, __builtin_amdgcn_readlane(__builtin_bit_cast(int, x), l));
}

// One-shot structure (R7 champion, 136 us): 2 rows per wave, wave retires
// after 6 fire-and-forget stores. Persistent variants (R8/R9) regressed:
// hardware wave churn overlaps loads/compute/stores across waves better
// than a software loop with per-iteration fences.
// R10 change: nontemporal output stores (nt bit) -> outputs bypass L2/L3
// allocation, so the 268MB of inputs stay L3-resident across timed replays
// (FETCH_SIZE was 131MB = half the inputs re-fetched every replay, evicted
// by 402MB/replay of write-allocated output traffic).
__global__ __launch_bounds__(256, 8) void pdf_resample_kernel(
    const float* __restrict__ weights,
    const float* __restrict__ ts,
    float* __restrict__ out,
    int num_rows)
{
    // Per-wave slices (2 rows/wave); no __syncthreads anywhere.
    __shared__ float4 s_pack[8][64];   // (cdf[i], ts[i], cdf[i+1], ts[i+1])
    __shared__ int    s_A[8][130];     // interleaved sample-bin scatter array

    const int lane = threadIdx.x & 63;
    const int wid  = threadIdx.x >> 6;
    const int row0 = (blockIdx.x * 4 + wid) * 2;
    if (row0 >= num_rows) return;      // num_rows is even -> row0+1 also valid

    const size_t g0 = (size_t)row0 * 64 + lane;
    const float w0 = weights[g0];
    const float t0 = ts[g0];
    const float w1 = weights[g0 + 64];
    const float t1 = ts[g0 + 64];

    float4* pack0 = s_pack[wid * 2];
    float4* pack1 = s_pack[wid * 2 + 1];
    int*    A0    = s_A[wid * 2];
    int*    A1    = s_A[wid * 2 + 1];

    const float flane = (float)lane;
    const float C127  = 1.0f / 127.0f;

    // ================= phase 1 (both rows, interleaved) =================
    const float wc0 = (lane < 63) ? w0 : 0.0f;
    const float wc1 = (lane < 63) ? w1 : 0.0f;
    const float sw0 = wscan_add_f(wc0);
    const float sw1 = wscan_add_f(wc1);

    const float wsumA = readlane_f(sw0, 63);
    const float wsumB = readlane_f(sw1, 63);
    const float padA  = fmaxf(EPSF - wsumA, 0.0f);
    const float padB  = fmaxf(EPSF - wsumB, 0.0f);
    const float p63A  = padA * (1.0f / 63.0f);
    const float p63B  = padB * (1.0f / 63.0f);
    const float rdenA = __builtin_amdgcn_rcpf(wsumA + padA);
    const float rdenB = __builtin_amdgcn_rcpf(wsumB + padB);

    // cv = cdf[lane+1]; monotone in lane. (Boundary proofs: R6/R7.)
    const float cv0 = fminf(1.0f, fmaf(flane + 1.0f, p63A, sw0) * rdenA);
    const float cv1 = fminf(1.0f, fmaf(flane + 1.0f, p63B, sw1) * rdenB);
    const float cdf_lo0 = dpp_up1_f(cv0);              // lane0 -> 0 via old=0
    const float cdf_lo1 = dpp_up1_f(cv1);
    // cdf_hi = cv unconditionally (proof R7); ts_hi via fmax (ts>0, lane63
    // DPP old=0 -> fmax restores t; sorted ts makes fmax a no-op elsewhere).
    const float ts_hi0 = fmaxf(dpp_dn1_f(t0), t0);
    const float ts_hi1 = fmaxf(dpp_dn1_f(t1), t1);

    pack0[lane] = make_float4(cdf_lo0, t0, cv0, ts_hi0);
    pack1[lane] = make_float4(cdf_lo1, t1, cv1, ts_hi1);
    ((int2*)A0)[lane] = make_int2(0, 0);               // init slots 0..127
    ((int2*)A1)[lane] = make_int2(0, 0);

    // exact r = #{ j in [0,128): fl(j*C127) < cdf_lo }; est rel-err <= 2^-24
    // -> true r in {base..base+2} (window proven R5).
    int b0 = (int)(cdf_lo0 * 127.0f); b0 = (b0 > 125) ? 125 : b0;
    int b1 = (int)(cdf_lo1 * 127.0f); b1 = (b1 > 125) ? 125 : b1;
    int r0 = b0, r1 = b1;
    #pragma unroll
    for (int d = 0; d < 3; ++d) {
        const int j0 = b0 + d;
        const int j1 = b1 + d;
        if ((float)j0 * C127 < cdf_lo0) r0 = j0 + 1;
        if ((float)j1 * C127 < cdf_lo1) r1 = j1 + 1;
    }

    // Interleaved dedup-scatter: A'[2r] for r<64, A'[2r-127] for r>=64
    // (r=128 -> slot 129: allocated, never read). Injective in r.
    const int mr0 = (r0 < 64) ? (2 * r0) : (2 * r0 - 127);
    const int mr1 = (r1 < 64) ? (2 * r1) : (2 * r1 - 127);
    const int rn0 = dpp_dn1_i(r0);                     // lane63 -> 0 (forced)
    const int rn1 = dpp_dn1_i(r1);
    if ((lane == 63) || (rn0 > r0)) A0[mr0] = lane;    // last k of each r-run
    if ((lane == 63) || (rn1 > r1)) A1[mr1] = lane;

    // merge position of ts[lane] is exactly r (identity proven R6); fire early.
    float* __restrict__ orow0 = out + (size_t)row0 * 192;
    float* __restrict__ orow1 = orow0 + 192;
    __builtin_nontemporal_store(t0, &orow0[lane + r0]);
    __builtin_nontemporal_store(t1, &orow1[lane + r1]);

    // one wave-local fence covers all LDS writes of both rows
    asm volatile("s_waitcnt lgkmcnt(0)" ::: "memory");

    // ================= phase 2 (both rows, interleaved) =================
    const int2 av0 = ((const int2*)A0)[lane];
    const int2 av1 = ((const int2*)A1)[lane];
    int i00 = wscan_max_i(av0.x);
    int i10 = wscan_max_i(av1.x);
    const int cA0 = __builtin_amdgcn_readlane(i00, 63);
    const int cA1 = __builtin_amdgcn_readlane(i10, 63);
    int i01 = wscan_max_i(av0.y); i01 = (i01 > cA0) ? i01 : cA0;
    int i11 = wscan_max_i(av1.y); i11 = (i11 > cA1) ? i11 : cA1;

    const float u0 = flane * C127;
    const float u1 = (flane + 64.0f) * C127;
    const float4 p00 = pack0[i00];
    const float4 p01 = pack0[i01];
    const float4 p10 = pack1[i10];
    const float4 p11 = pack1[i11];

    float d00 = p00.z - p00.x; d00 = (d00 < EPSF) ? 1.0f : d00;
    float d01 = p01.z - p01.x; d01 = (d01 < EPSF) ? 1.0f : d01;
    float d10 = p10.z - p10.x; d10 = (d10 < EPSF) ? 1.0f : d10;
    float d11 = p11.z - p11.x; d11 = (d11 < EPSF) ? 1.0f : d11;
    const float nt00 = p00.y + ((u0 - p00.x) * __builtin_amdgcn_rcpf(d00)) * (p00.w - p00.y);
    const float nt01 = p01.y + ((u1 - p01.x) * __builtin_amdgcn_rcpf(d01)) * (p01.w - p01.y);
    const float nt10 = p10.y + ((u0 - p10.x) * __builtin_amdgcn_rcpf(d10)) * (p10.w - p10.y);
    const float nt11 = p11.y + ((u1 - p11.x) * __builtin_amdgcn_rcpf(d11)) * (p11.w - p11.y);

    // merge positions of samples: j + i_j + 1 (t-first tie order);
    // permutation of [0,192) guaranteed combinatorially (monotone r + inverse i).
    __builtin_nontemporal_store(nt00, &orow0[lane + i00 + 1]);
    __builtin_nontemporal_store(nt01, &orow0[lane + 64 + i01 + 1]);
    __builtin_nontemporal_store(nt10, &orow1[lane + i10 + 1]);
    __builtin_nontemporal_store(nt11, &orow1[lane + 64 + i11 + 1]);
}

extern "C" void kernel_launch(void* const* d_in, const int* in_sizes, int n_in,
                              void* d_out, int out_size, void* d_ws, size_t ws_size,
                              hipStream_t stream) {
    const float* weights = (const float*)d_in[0];
    const float* ts      = (const float*)d_in[1];
    float* out           = (float*)d_out;
    const int num_rows = in_sizes[0] / 64;         // 524288 (even)
    const int waves    = (num_rows + 1) / 2;       // 2 rows per wave
    const int blocks   = (waves + 3) / 4;          // 4 waves per block
    pdf_resample_kernel<<<blocks, 256, 0, stream>>>(weights, ts, out, num_rows);
}

// Round 12
// 99.105 us; speedup vs baseline: 2.2259x; 2.2259x over previous
//
#include <hip/hip_runtime.h>

#define EPSF 1e-5f

typedef float f32x4 __attribute__((ext_vector_type(4)));

// DPP move with old=0 (identity for add/max over nonnegative values; also
// provides the 0 boundary value for wave shifts).
#define DPPI(x, ctrl, rmask) \
    __builtin_amdgcn_update_dpp(0, (x), (ctrl), (rmask), 0xf, false)
#define DPPF(x, ctrl, rmask) \
    __builtin_bit_cast(float, __builtin_amdgcn_update_dpp(0, __builtin_bit_cast(int, (x)), (ctrl), (rmask), 0xf, false))

// Wave-wide shift-by-1 via gfx9 DPP (no DS pipe).
__device__ __forceinline__ float dpp_up1_f(float x) { return DPPF(x, 0x138, 0xf); }
__device__ __forceinline__ float dpp_dn1_f(float x) { return DPPF(x, 0x130, 0xf); }
__device__ __forceinline__ int   dpp_dn1_i(int   x) { return DPPI(x, 0x130, 0xf); }

// GCN wave64 inclusive scans: row_shr 1/2/4/8 + row_bcast:15 (rows 1,3) +
// row_bcast:31 (rows 2,3). Pure VALU. (Proven R3-R10.)
__device__ __forceinline__ float wscan_add_f(float x) {
    x += DPPF(x, 0x111, 0xf);
    x += DPPF(x, 0x112, 0xf);
    x += DPPF(x, 0x114, 0xf);
    x += DPPF(x, 0x118, 0xf);
    x += DPPF(x, 0x142, 0xa);
    x += DPPF(x, 0x143, 0xc);
    return x;
}
__device__ __forceinline__ int wscan_max_i(int x) {
    int y;
    y = DPPI(x, 0x111, 0xf); x = (x > y) ? x : y;
    y = DPPI(x, 0x112, 0xf); x = (x > y) ? x : y;
    y = DPPI(x, 0x114, 0xf); x = (x > y) ? x : y;
    y = DPPI(x, 0x118, 0xf); x = (x > y) ? x : y;
    y = DPPI(x, 0x142, 0xa); x = (x > y) ? x : y;
    y = DPPI(x, 0x143, 0xc); x = (x > y) ? x : y;
    return x;
}
__device__ __forceinline__ float readlane_f(float x, int l) {
    return __builtin_bit_cast(float, __builtin_amdgcn_readlane(__builtin_bit_cast(int, x), l));
}

// R7 one-shot structure (136 us champion) + LDS-staged output written as
// FULL-LINE nontemporal float4 bursts:
//  - R10 showed scattered nt dword stores cause partial-line HBM RMW
//    (WRITE_SIZE 393->708MB) + store backpressure. nt needs full lines.
//  - Staging the 384 outputs of the pair in LDS and storing 96 contiguous
//    float4 (1KB/wave-instr) gives dense lines; nt stops L2/L3 write
//    allocation, so the 268MB of inputs stay L3-resident across replays
//    (FETCH_SIZE was 131MB = re-fetch of evicted input halves).
//  - The out-buffer OVERLAYS s_pack (dead after the gathers; same-wave DS
//    ops execute in order, and the accesses alias the same shared array so
//    the compiler preserves program order) -> LDS stays 12.2KB, 8 blocks/CU.
__global__ __launch_bounds__(256, 8) void pdf_resample_kernel(
    const float* __restrict__ weights,
    const float* __restrict__ ts,
    float* __restrict__ out,
    int num_rows)
{
    // Per-wave slices (2 rows/wave); no __syncthreads anywhere.
    __shared__ float4 s_pack[8][64];   // (cdf[i], ts[i], cdf[i+1], ts[i+1]); later reused as out-stage
    __shared__ int    s_A[8][130];     // interleaved sample-bin scatter array

    const int lane = threadIdx.x & 63;
    const int wid  = threadIdx.x >> 6;
    const int row0 = (blockIdx.x * 4 + wid) * 2;
    if (row0 >= num_rows) return;      // num_rows is even -> row0+1 also valid

    const size_t g0 = (size_t)row0 * 64 + lane;
    const float w0 = weights[g0];
    const float t0 = ts[g0];
    const float w1 = weights[g0 + 64];
    const float t1 = ts[g0 + 64];

    float4* pack0 = s_pack[wid * 2];
    float4* pack1 = s_pack[wid * 2 + 1];
    int*    A0    = s_A[wid * 2];
    int*    A1    = s_A[wid * 2 + 1];

    const float flane = (float)lane;
    const float C127  = 1.0f / 127.0f;

    // ================= phase 1 (both rows, interleaved) =================
    const float wc0 = (lane < 63) ? w0 : 0.0f;
    const float wc1 = (lane < 63) ? w1 : 0.0f;
    const float sw0 = wscan_add_f(wc0);
    const float sw1 = wscan_add_f(wc1);

    const float wsumA = readlane_f(sw0, 63);
    const float wsumB = readlane_f(sw1, 63);
    const float padA  = fmaxf(EPSF - wsumA, 0.0f);
    const float padB  = fmaxf(EPSF - wsumB, 0.0f);
    const float p63A  = padA * (1.0f / 63.0f);
    const float p63B  = padB * (1.0f / 63.0f);
    const float rdenA = __builtin_amdgcn_rcpf(wsumA + padA);
    const float rdenB = __builtin_amdgcn_rcpf(wsumB + padB);

    // cv = cdf[lane+1]; monotone in lane. (Boundary proofs: R6/R7.)
    const float cv0 = fminf(1.0f, fmaf(flane + 1.0f, p63A, sw0) * rdenA);
    const float cv1 = fminf(1.0f, fmaf(flane + 1.0f, p63B, sw1) * rdenB);
    const float cdf_lo0 = dpp_up1_f(cv0);              // lane0 -> 0 via old=0
    const float cdf_lo1 = dpp_up1_f(cv1);
    // cdf_hi = cv unconditionally (proof R7); ts_hi via fmax (ts>0, lane63
    // DPP old=0 -> fmax restores t; sorted ts makes fmax a no-op elsewhere).
    const float ts_hi0 = fmaxf(dpp_dn1_f(t0), t0);
    const float ts_hi1 = fmaxf(dpp_dn1_f(t1), t1);

    pack0[lane] = make_float4(cdf_lo0, t0, cv0, ts_hi0);
    pack1[lane] = make_float4(cdf_lo1, t1, cv1, ts_hi1);
    ((int2*)A0)[lane] = make_int2(0, 0);               // init slots 0..127
    ((int2*)A1)[lane] = make_int2(0, 0);

    // exact r = #{ j in [0,128): fl(j*C127) < cdf_lo }; est rel-err <= 2^-24
    // -> true r in {base..base+2} (window proven R5).
    int b0 = (int)(cdf_lo0 * 127.0f); b0 = (b0 > 125) ? 125 : b0;
    int b1 = (int)(cdf_lo1 * 127.0f); b1 = (b1 > 125) ? 125 : b1;
    int r0 = b0, r1 = b1;
    #pragma unroll
    for (int d = 0; d < 3; ++d) {
        const int j0 = b0 + d;
        const int j1 = b1 + d;
        if ((float)j0 * C127 < cdf_lo0) r0 = j0 + 1;
        if ((float)j1 * C127 < cdf_lo1) r1 = j1 + 1;
    }

    // Interleaved dedup-scatter: A'[2r] for r<64, A'[2r-127] for r>=64
    // (r=128 -> slot 129: allocated, never read). Injective in r.
    const int mr0 = (r0 < 64) ? (2 * r0) : (2 * r0 - 127);
    const int mr1 = (r1 < 64) ? (2 * r1) : (2 * r1 - 127);
    const int rn0 = dpp_dn1_i(r0);                     // lane63 -> 0 (forced)
    const int rn1 = dpp_dn1_i(r1);
    if ((lane == 63) || (rn0 > r0)) A0[mr0] = lane;    // last k of each r-run
    if ((lane == 63) || (rn1 > r1)) A1[mr1] = lane;

    // wave-local fence: covers pack/A writes of both rows
    asm volatile("s_waitcnt lgkmcnt(0)" ::: "memory");

    // ================= phase 2 (both rows, interleaved) =================
    const int2 av0 = ((const int2*)A0)[lane];
    const int2 av1 = ((const int2*)A1)[lane];
    int i00 = wscan_max_i(av0.x);
    int i10 = wscan_max_i(av1.x);
    const int cA0 = __builtin_amdgcn_readlane(i00, 63);
    const int cA1 = __builtin_amdgcn_readlane(i10, 63);
    int i01 = wscan_max_i(av0.y); i01 = (i01 > cA0) ? i01 : cA0;
    int i11 = wscan_max_i(av1.y); i11 = (i11 > cA1) ? i11 : cA1;

    const float u0 = flane * C127;
    const float u1 = (flane + 64.0f) * C127;
    const float4 p00 = pack0[i00];
    const float4 p01 = pack0[i01];
    const float4 p10 = pack1[i10];
    const float4 p11 = pack1[i11];

    float d00 = p00.z - p00.x; d00 = (d00 < EPSF) ? 1.0f : d00;
    float d01 = p01.z - p01.x; d01 = (d01 < EPSF) ? 1.0f : d01;
    float d10 = p10.z - p10.x; d10 = (d10 < EPSF) ? 1.0f : d10;
    float d11 = p11.z - p11.x; d11 = (d11 < EPSF) ? 1.0f : d11;
    const float nt00 = p00.y + ((u0 - p00.x) * __builtin_amdgcn_rcpf(d00)) * (p00.w - p00.y);
    const float nt01 = p01.y + ((u1 - p01.x) * __builtin_amdgcn_rcpf(d01)) * (p01.w - p01.y);
    const float nt10 = p10.y + ((u0 - p10.x) * __builtin_amdgcn_rcpf(d10)) * (p10.w - p10.y);
    const float nt11 = p11.y + ((u1 - p11.x) * __builtin_amdgcn_rcpf(d11)) * (p11.w - p11.y);

    // ---- stage both rows' outputs in LDS (overlays s_pack: all pack reads
    // above are issued before these writes; same-wave DS ops are in-order) ----
    float* ob = (float*)pack0;         // 512 floats span pack0+pack1 >= 384
    // positions: ts_i -> i + r_i ; nts_j -> j + i_j + 1 (identities proven R6)
    ob[lane + r0]            = t0;
    ob[lane + i00 + 1]       = nt00;
    ob[lane + 64 + i01 + 1]  = nt01;
    ob[192 + lane + r1]            = t1;
    ob[192 + lane + i10 + 1]       = nt10;
    ob[192 + lane + 64 + i11 + 1]  = nt11;

    asm volatile("s_waitcnt lgkmcnt(0)" ::: "memory");

    // ---- full-line nontemporal writeback: 96 x 16B = 2 rows ----
    const f32x4* o4 = (const f32x4*)ob;
    f32x4* __restrict__ g4 = (f32x4*)(out + (size_t)row0 * 192);  // 768B-aligned
    const f32x4 v0 = o4[lane];
    __builtin_nontemporal_store(v0, &g4[lane]);
    if (lane < 32) {
        const f32x4 v1 = o4[64 + lane];
        __builtin_nontemporal_store(v1, &g4[64 + lane]);
    }
}

extern "C" void kernel_launch(void* const* d_in, const int* in_sizes, int n_in,
                              void* d_out, int out_size, void* d_ws, size_t ws_size,
                              hipStream_t stream) {
    const float* weights = (const float*)d_in[0];
    const float* ts      = (const float*)d_in[1];
    float* out           = (float*)d_out;
    const int num_rows = in_sizes[0] / 64;         // 524288 (even)
    const int waves    = (num_rows + 1) / 2;       // 2 rows per wave
    const int blocks   = (waves + 3) / 4;          // 4 waves per block
    pdf_resample_kernel<<<blocks, 256, 0, stream>>>(weights, ts, out, num_rows);
}